// Round 14
// baseline (1403.603 us; speedup 1.0000x reference)
//
#include <hip/hip_runtime.h>

// ---------------------------------------------------------------------------
// Problem constants
// ---------------------------------------------------------------------------
constexpr int NN = 50000;            // nodes
constexpr int NE = 800000;           // edges (before self loops)
constexpr int NP = 262144;           // pairs
constexpr int ET = NE + NN;          // edges incl self loops

using short8 = __attribute__((ext_vector_type(8))) short;
using f32x4  = __attribute__((ext_vector_type(4))) float;

__device__ __forceinline__ ushort f2b(float f) {   // fp32 -> bf16 RNE
  unsigned u = __float_as_uint(f);
  return (ushort)((u + 0x7FFFu + ((u >> 16) & 1u)) >> 16);
}
__device__ __forceinline__ float b2f(ushort b) {
  return __uint_as_float(((unsigned)b) << 16);
}

// global -> LDS direct copy, 16B per lane (wave-linear LDS destination)
#define GLOAD_LDS16(gp, lp)                                                    \
  __builtin_amdgcn_global_load_lds(                                            \
      (const __attribute__((address_space(1))) void*)(gp),                     \
      (__attribute__((address_space(3))) void*)(lp), 16, 0, 0)

// ---------------------------------------------------------------------------
// bf16 MFMA GEMM: C[M,N] = A[M,Kpad] @ BT[Npad,Kpad]^T  (+bias)
// 128x128 block tile, BK=32 (R5 vs R8: BK32 >= BK64 by ~22us; 17KB LDS ->
// ~5 blocks/CU vs 4), 4 waves of 64x64 (4x4 grid of 16x16x32 MFMA).
//
// LDS XOR-SWIZZLE v2 (pair-row): [128][32] bf16 rows are 64B. Fragment read
// slot = ja ^ ((row>>1)&3): start bank-group = 16*(row&1) + 4*slot; a
// quarter-wave's 16 rows cover 8 distinct 4-bank groups x 2 lanes = free
// tier (m136). Source chunk pre-swizzled with the same involution
// (c8s = c8 ^ ((m>>1)&3)); LDS dest stays linear (m104).
// R12's BK64 slot=ja^(row&7) variant measured only -33.6us (partial fix).
// STATS: per-column sum/sumsq of output -> stats (N==128 only, M%128==0).
// ---------------------------------------------------------------------------
template<bool GATHER, bool OUT_BF16, bool STATS>
__global__ __launch_bounds__(256)
void mfma_gemm(const ushort* __restrict__ A, const ushort* __restrict__ BT,
               void* __restrict__ Cp, int M, int N, int Kpad, int Cld,
               const float* __restrict__ bias,
               const int* __restrict__ idx0, const int* __restrict__ idx1,
               double* __restrict__ stats)
{
  __shared__ __align__(16) ushort As[128 * 32];   // linear, BK=32
  __shared__ __align__(16) ushort Bs[128 * 32];
  __shared__ int idxs[256];
  const int tid = threadIdx.x;
  const int lane = tid & 63;
  const int wave = tid >> 6;
  const int row0 = blockIdx.y * 128, col0 = blockIdx.x * 128;
  const int wm = (wave >> 1) * 64, wn = (wave & 1) * 64;
  const int lrow = lane & 15, ja = lane >> 4;     // logical 16B chunk 0..3

  if constexpr (GATHER) {
    if (tid < 128) {
      int r = row0 + tid;
      idxs[tid]       = (r < M) ? idx0[r] : 0;
      idxs[128 + tid] = (r < M) ? idx1[r] : 0;
    }
    __syncthreads();
  }

  f32x4 acc[4][4];
  #pragma unroll
  for (int i = 0; i < 4; ++i)
    #pragma unroll
    for (int j = 0; j < 4; ++j)
      acc[i][j] = (f32x4){0.f, 0.f, 0.f, 0.f};

  for (int kt = 0; kt < Kpad; kt += 32) {
    // ---- stage A: 512 chunks of 16B, 2/thread; source chunk swizzled ----
    // wave w covers rows [w*16, w*16+16) and [64+w*16, ...): 16-row groups,
    // mask boundary (M-row0=80) is 16-aligned -> whole-wave predication.
    #pragma unroll
    for (int c = tid; c < 512; c += 256) {
      int m = c >> 2, c8 = c & 3;             // LDS row, LDS chunk slot
      int c8s = c8 ^ ((m >> 1) & 3);          // logical (global) chunk
      int r = row0 + m;
      if (r < M) {
        const ushort* sp;
        if (GATHER) {
          int kk = kt + c8s * 8;              // offsets 0..24 within 32-tile:
          int node = (kk < 256) ? idxs[m] : idxs[128 + m];  // never straddles
          sp = A + (size_t)node * 256 + (kk & 255);
        } else {
          sp = A + (size_t)r * Kpad + kt + c8s * 8;
        }
        GLOAD_LDS16(sp, As + c * 8);
      }
    }
    // ---- stage B (in-bounds: BT padded to Npad x Kpad), same swizzle ----
    #pragma unroll
    for (int c = tid; c < 512; c += 256) {
      int n = c >> 2, c8 = c & 3;
      int c8s = c8 ^ ((n >> 1) & 3);
      GLOAD_LDS16(BT + (size_t)(col0 + n) * Kpad + kt + c8s * 8, Bs + c * 8);
    }
    __syncthreads();

    short8 af[4], bfr[4];
    #pragma unroll
    for (int i = 0; i < 4; ++i) {
      int ra = wm + i * 16 + lrow;
      af[i] = *(const short8*)(As + ra * 32 + ((ja ^ ((ra >> 1) & 3)) << 3));
    }
    #pragma unroll
    for (int j = 0; j < 4; ++j) {
      int rb = wn + j * 16 + lrow;
      bfr[j] = *(const short8*)(Bs + rb * 32 + ((ja ^ ((rb >> 1) & 3)) << 3));
    }
    #pragma unroll
    for (int i = 0; i < 4; ++i)
      #pragma unroll
      for (int j = 0; j < 4; ++j)
        acc[i][j] = __builtin_amdgcn_mfma_f32_16x16x32_bf16(af[i], bfr[j],
                                                            acc[i][j], 0, 0, 0);
    __syncthreads();
  }

  // epilogue: D mapping col=lane&15, row=(lane>>4)*4+reg
  float* sacc = (float*)As;                 // reuse LDS: [128]{sum,sumsq}
  if constexpr (STATS) {
    sacc[tid] = 0.f;
    __syncthreads();
  }
  float cs[4] = {0.f, 0.f, 0.f, 0.f}, cq[4] = {0.f, 0.f, 0.f, 0.f};
  #pragma unroll
  for (int i = 0; i < 4; ++i) {
    int r0 = row0 + wm + i * 16 + (lane >> 4) * 4;
    #pragma unroll
    for (int j = 0; j < 4; ++j) {
      int col = col0 + wn + j * 16 + lrow;
      if (col >= N) continue;
      float bv = bias ? bias[col] : 0.f;
      #pragma unroll
      for (int rg = 0; rg < 4; ++rg) {
        int row = r0 + rg;
        if (row >= M) continue;
        float val = acc[i][j][rg] + bv;
        if (OUT_BF16)
          ((ushort*)Cp)[(size_t)row * Cld + col] = f2b(val);
        else
          ((float*)Cp)[(size_t)row * Cld + col] = val;
        if (STATS) { cs[j] += val; cq[j] += val * val; }
      }
    }
  }
  if constexpr (STATS) {
    #pragma unroll
    for (int j = 0; j < 4; ++j) {
      int cl = wn + j * 16 + lrow;          // local col (N==128, col0==0)
      atomicAdd(&sacc[2 * cl + 0], cs[j]);
      atomicAdd(&sacc[2 * cl + 1], cq[j]);
    }
    __syncthreads();
    if (tid < 128) {
      unsafeAtomicAdd(&stats[tid],       (double)sacc[2 * tid + 0]);
      unsafeAtomicAdd(&stats[128 + tid], (double)sacc[2 * tid + 1]);
    }
  }
}

// ---------------------------------------------------------------------------
// Weight prep: all 5 transposes in one kernel. W[K][N] -> BT[Npad][Kpad] bf16.
// ---------------------------------------------------------------------------
__global__ void prep_weights(const float* __restrict__ W1, ushort* __restrict__ W1T,
                             const float* __restrict__ W2, ushort* __restrict__ W2T,
                             const float* __restrict__ lw1, ushort* __restrict__ LW1T,
                             const float* __restrict__ lw2, ushort* __restrict__ LW2T,
                             const float* __restrict__ fw, ushort* __restrict__ FWT)
{
  int i = blockIdx.x * blockDim.x + threadIdx.x;
  const float* W; ushort* BT; int K, N, Kpad;
  if (i < 294912)      { W = W1;  BT = W1T;  K = 572; N = 512; Kpad = 576; }
  else if (i < 425984) { i -= 294912; W = W2;  BT = W2T;  K = 256; N = 512; Kpad = 256; }
  else if (i < 491520) { i -= 425984; W = lw1; BT = LW1T; K = 512; N = 128; Kpad = 512; }
  else if (i < 507904) { i -= 491520; W = lw2; BT = LW2T; K = 128; N = 128; Kpad = 128; }
  else                 { i -= 507904; W = fw;  BT = FWT;  K = 128; N = 65;  Kpad = 128; }
  int n = i / Kpad, k = i % Kpad;
  float v = (n < N && k < K) ? W[(size_t)k * N + n] : 0.f;
  BT[i] = f2b(v);
}

// x[NN][572] fp32 -> xb[NN][576] bf16 (zero padded), 4 cols/thread
__global__ void conv_x(const float* __restrict__ x, ushort* __restrict__ xb)
{
  int i = blockIdx.x * blockDim.x + threadIdx.x;
  if (i >= NN * 144) return;
  int r = i / 144, c4 = (i % 144) * 4;
  ushort4 o = {0, 0, 0, 0};
  if (c4 < 572) {           // c4 <= 568 -> full float4 in-bounds
    float4 v = *(const float4*)(x + (size_t)r * 572 + c4);
    o.x = f2b(v.x); o.y = f2b(v.y); o.z = f2b(v.z); o.w = f2b(v.w);
  }
  *(ushort4*)(xb + (size_t)r * 576 + c4) = o;
}

// ---------------------------------------------------------------------------
// CSR build (graph identical for both layers -> build once per call)
// ---------------------------------------------------------------------------
__global__ void deg_count(const int* __restrict__ ei, int* __restrict__ deg)
{
  int e = blockIdx.x * blockDim.x + threadIdx.x;
  if (e >= ET) return;
  int dst = (e < NE) ? ei[NE + e] : e - NE;
  atomicAdd(&deg[dst], 1);
}

__global__ __launch_bounds__(1024)
void scan_deg(const int* __restrict__ deg, int* __restrict__ rowptr,
              int* __restrict__ cursor)
{
  __shared__ int tot[1024];
  const int t = threadIdx.x;
  const int CH = (NN + 1023) / 1024;
  const int base = t * CH;
  int s = 0;
  for (int i = 0; i < CH; ++i) {
    int idx = base + i;
    if (idx < NN) s += deg[idx];
  }
  tot[t] = s;
  __syncthreads();
  for (int off = 1; off < 1024; off <<= 1) {
    int v = (t >= off) ? tot[t - off] : 0;
    __syncthreads();
    tot[t] += v;
    __syncthreads();
  }
  int run = (t == 0) ? 0 : tot[t - 1];
  for (int i = 0; i < CH; ++i) {
    int idx = base + i;
    if (idx <= NN) { rowptr[idx] = run; if (idx < NN) cursor[idx] = run; }
    if (idx < NN) run += deg[idx];
  }
}

__global__ void scatter_edges(const int* __restrict__ ei, int* __restrict__ cursor,
                              int* __restrict__ csr_src)
{
  int e = blockIdx.x * blockDim.x + threadIdx.x;
  if (e >= ET) return;
  int src, dst;
  if (e < NE) { src = ei[e]; dst = ei[NE + e]; }
  else        { src = dst = e - NE; }
  int pos = atomicAdd(&cursor[dst], 1);
  csr_src[pos] = src;
}

// ---------------------------------------------------------------------------
// GAT helpers (h in bf16)
// ---------------------------------------------------------------------------

// one wave per node, both heads: lane loads 8 contiguous bf16 (16 B)
__global__ void node_coeffs(const ushort* __restrict__ hb,
                            const float* __restrict__ a_src,
                            const float* __restrict__ a_dst,
                            float* __restrict__ s_n, float* __restrict__ d_n)
{
  int node = (blockIdx.x * blockDim.x + threadIdx.x) >> 6;
  int lane = threadIdx.x & 63;
  if (node >= NN) return;
  int head = lane >> 5;                 // lanes 0-31 head0, 32-63 head1
  int cidx = (lane * 8) & 255;          // col within head
  short8 hv = *(const short8*)(hb + (size_t)node * 512 + lane * 8);
  float4 a0 = *(const float4*)(a_src + head * 256 + cidx);
  float4 a1 = *(const float4*)(a_src + head * 256 + cidx + 4);
  float4 d0 = *(const float4*)(a_dst + head * 256 + cidx);
  float4 d1 = *(const float4*)(a_dst + head * 256 + cidx + 4);
  float h0 = b2f((ushort)hv[0]), h1 = b2f((ushort)hv[1]);
  float h2 = b2f((ushort)hv[2]), h3 = b2f((ushort)hv[3]);
  float h4 = b2f((ushort)hv[4]), h5 = b2f((ushort)hv[5]);
  float h6 = b2f((ushort)hv[6]), h7 = b2f((ushort)hv[7]);
  float ss = h0*a0.x + h1*a0.y + h2*a0.z + h3*a0.w
           + h4*a1.x + h5*a1.y + h6*a1.z + h7*a1.w;
  float dd = h0*d0.x + h1*d0.y + h2*d0.z + h3*d0.w
           + h4*d1.x + h5*d1.y + h6*d1.z + h7*d1.w;
  #pragma unroll
  for (int off = 16; off > 0; off >>= 1) {   // reduce within 32-lane half
    ss += __shfl_xor(ss, off);
    dd += __shfl_xor(dd, off);
  }
  if ((lane & 31) == 0) {
    s_n[node * 2 + head] = ss;
    d_n[node * 2 + head] = dd;
  }
}

// Measured-185us shape (4 dsts/wave, 256-thread blocks), now range-split into
// TWO dispatches (dst0 param; per-block work identical, purely for top-5
// profiling visibility — stats adds are atomic-additive so split is exact).
__global__ __launch_bounds__(256)
void gat_aggregate(const int* __restrict__ rowptr, const int* __restrict__ csr_src,
                   const ushort* __restrict__ hb,
                   const float* __restrict__ s_n, const float* __restrict__ d_n,
                   const float* __restrict__ bias, float* __restrict__ outp,
                   double* __restrict__ stats, int dst0)
{
  __shared__ float sacc[512];               // [256] sum, [256] sumsq
  sacc[threadIdx.x] = 0.f;
  sacc[256 + threadIdx.x] = 0.f;
  __syncthreads();

  const int wave = threadIdx.x >> 6, lane = threadIdx.x & 63;
  const int base = dst0 + blockIdx.x * 16 + wave * 4;
  const float4 bb = *(const float4*)(bias + lane * 4);
  const float2* sn2 = (const float2*)s_n;

  float ps[4] = {0.f, 0.f, 0.f, 0.f}, pq[4] = {0.f, 0.f, 0.f, 0.f};

  for (int n = 0; n < 4; ++n) {
    const int dst = base + n;
    if (dst >= NN) continue;                // wave-uniform
    const int beg = rowptr[dst], end = rowptr[dst + 1];
    const float d0 = d_n[dst * 2 + 0], d1 = d_n[dst * 2 + 1];

    // ---- scan 1: per-head max (strided across lanes) ----
    float m0 = -1e30f, m1 = -1e30f;
    for (int i = beg + lane; i < end; i += 64) {
      float2 sv = sn2[csr_src[i]];
      float a0 = sv.x + d0; a0 = a0 > 0.f ? a0 : 0.2f * a0;
      float a1 = sv.y + d1; a1 = a1 > 0.f ? a1 : 0.2f * a1;
      m0 = fmaxf(m0, a0); m1 = fmaxf(m1, a1);
    }
    #pragma unroll
    for (int off = 32; off > 0; off >>= 1) {
      m0 = fmaxf(m0, __shfl_xor(m0, off));
      m1 = fmaxf(m1, __shfl_xor(m1, off));
    }

    // ---- scan 2: unnormalized aggregation + partition sum, 4x unroll ----
    float z0 = 0.f, z1 = 0.f;
    float4 acc0 = {0.f, 0.f, 0.f, 0.f};
    float4 acc1 = {0.f, 0.f, 0.f, 0.f};
    int i = beg;
    for (; i + 4 <= end; i += 4) {          // 8 outstanding 8B gathers/lane
      int s[4];
      #pragma unroll
      for (int u = 0; u < 4; ++u) s[u] = csr_src[i + u];
      ushort4 h0[4], h1[4]; float2 sv[4];
      #pragma unroll
      for (int u = 0; u < 4; ++u) {
        h0[u] = *(const ushort4*)(hb + (size_t)s[u] * 512 + lane * 4);
        h1[u] = *(const ushort4*)(hb + (size_t)s[u] * 512 + 256 + lane * 4);
        sv[u] = sn2[s[u]];
      }
      #pragma unroll
      for (int u = 0; u < 4; ++u) {
        float a0 = sv[u].x + d0; a0 = a0 > 0.f ? a0 : 0.2f * a0;
        float a1 = sv[u].y + d1; a1 = a1 > 0.f ? a1 : 0.2f * a1;
        float e0 = __expf(a0 - m0), e1 = __expf(a1 - m1);
        z0 += e0; z1 += e1;
        acc0.x = fmaf(b2f(h0[u].x), e0, acc0.x);
        acc0.y = fmaf(b2f(h0[u].y), e0, acc0.y);
        acc0.z = fmaf(b2f(h0[u].z), e0, acc0.z);
        acc0.w = fmaf(b2f(h0[u].w), e0, acc0.w);
        acc1.x = fmaf(b2f(h1[u].x), e1, acc1.x);
        acc1.y = fmaf(b2f(h1[u].y), e1, acc1.y);
        acc1.z = fmaf(b2f(h1[u].z), e1, acc1.z);
        acc1.w = fmaf(b2f(h1[u].w), e1, acc1.w);
      }
    }
    for (; i < end; ++i) {
      int s = csr_src[i];
      float2 sv = sn2[s];
      ushort4 u0 = *(const ushort4*)(hb + (size_t)s * 512 + lane * 4);
      ushort4 u1 = *(const ushort4*)(hb + (size_t)s * 512 + 256 + lane * 4);
      float a0 = sv.x + d0; a0 = a0 > 0.f ? a0 : 0.2f * a0;
      float a1 = sv.y + d1; a1 = a1 > 0.f ? a1 : 0.2f * a1;
      float e0 = __expf(a0 - m0), e1 = __expf(a1 - m1);
      z0 += e0; z1 += e1;
      acc0.x = fmaf(b2f(u0.x), e0, acc0.x); acc0.y = fmaf(b2f(u0.y), e0, acc0.y);
      acc0.z = fmaf(b2f(u0.z), e0, acc0.z); acc0.w = fmaf(b2f(u0.w), e0, acc0.w);
      acc1.x = fmaf(b2f(u1.x), e1, acc1.x); acc1.y = fmaf(b2f(u1.y), e1, acc1.y);
      acc1.z = fmaf(b2f(u1.z), e1, acc1.z); acc1.w = fmaf(b2f(u1.w), e1, acc1.w);
    }

    const float rz0 = 1.f / (z0 + 1e-16f);
    const float rz1 = 1.f / (z1 + 1e-16f);
    float4 o;
    o.x = 0.5f * (acc0.x * rz0 + acc1.x * rz1) + bb.x;
    o.y = 0.5f * (acc0.y * rz0 + acc1.y * rz1) + bb.y;
    o.z = 0.5f * (acc0.z * rz0 + acc1.z * rz1) + bb.z;
    o.w = 0.5f * (acc0.w * rz0 + acc1.w * rz1) + bb.w;
    *(float4*)(outp + (size_t)dst * 256 + lane * 4) = o;

    ps[0] += o.x; ps[1] += o.y; ps[2] += o.z; ps[3] += o.w;
    pq[0] += o.x * o.x; pq[1] += o.y * o.y;
    pq[2] += o.z * o.z; pq[3] += o.w * o.w;
  }

  // one set of LDS atomics per wave
  const int c = lane * 4;
  atomicAdd(&sacc[c + 0], ps[0]); atomicAdd(&sacc[c + 1], ps[1]);
  atomicAdd(&sacc[c + 2], ps[2]); atomicAdd(&sacc[c + 3], ps[3]);
  atomicAdd(&sacc[256 + c + 0], pq[0]); atomicAdd(&sacc[256 + c + 1], pq[1]);
  atomicAdd(&sacc[256 + c + 2], pq[2]); atomicAdd(&sacc[256 + c + 3], pq[3]);
  __syncthreads();
  unsafeAtomicAdd(&stats[threadIdx.x],         (double)sacc[threadIdx.x]);
  unsafeAtomicAdd(&stats[256 + threadIdx.x],   (double)sacc[256 + threadIdx.x]);
}

// ---------------------------------------------------------------------------
// BatchNorm apply (+ReLU) -> bf16; scale/shift computed inline from stats
// ---------------------------------------------------------------------------
__global__ void bn_apply_relu_b4(const float* __restrict__ x, ushort* __restrict__ y,
                                 const double* __restrict__ stats,
                                 const float* __restrict__ g, const float* __restrict__ b,
                                 int total4, int cols, float inv_rows)
{
  int i = blockIdx.x * blockDim.x + threadIdx.x;
  if (i >= total4) return;
  int base = i * 4;
  int c = base % cols;                  // cols % 4 == 0 -> same row, 4 cols
  float4 xv = *(const float4*)(x + base);
  float4 gv = *(const float4*)(g + c);
  float4 bv = *(const float4*)(b + c);
  ushort4 o;
  #pragma unroll
  for (int k = 0; k < 4; ++k) {
    float mean = (float)(stats[c + k] * (double)inv_rows);
    float var = (float)(stats[cols + c + k] * (double)inv_rows) - mean * mean;
    float sc = ((const float*)&gv)[k] * rsqrtf(var + 1e-5f);
    float sh = ((const float*)&bv)[k] - mean * sc;
    float v = fmaxf(fmaf(((const float*)&xv)[k], sc, sh), 0.f);
    ((ushort*)&o)[k] = f2b(v);
  }
  *(ushort4*)(y + base) = o;
}

// ---------------------------------------------------------------------------
// Host-side GAT layer
// ---------------------------------------------------------------------------
static void gat_layer(const ushort* ain, int Kpad, const ushort* WT,
                      const float* asrc, const float* adst, const float* bias,
                      const float* bng, const float* bnb,
                      const int* rowptr, const int* csr_src,
                      ushort* hb, float* t, ushort* featb,
                      float* s_n, float* d_n, double* stats, hipStream_t st)
{
  dim3 b256(256);
  mfma_gemm<false, true, false><<<dim3(4, 391), b256, 0, st>>>(
      ain, WT, hb, NN, 512, Kpad, 512, nullptr, nullptr, nullptr, nullptr);
  node_coeffs<<<(NN + 3) / 4, b256, 0, st>>>(hb, asrc, adst, s_n, d_n);
  // range-split (4-dst/wave shape unchanged): 1563*16=25008, then the rest
  gat_aggregate<<<1563, b256, 0, st>>>(rowptr, csr_src, hb,
                                       s_n, d_n, bias, t, stats, 0);
  gat_aggregate<<<1562, b256, 0, st>>>(rowptr, csr_src, hb,
                                       s_n, d_n, bias, t, stats, 25008);
  bn_apply_relu_b4<<<(NN * 64 + 255) / 256, b256, 0, st>>>(
      t, featb, stats, bng, bnb, NN * 64, 256, 1.0f / NN);
}

// ---------------------------------------------------------------------------
// kernel_launch
// ---------------------------------------------------------------------------
extern "C" void kernel_launch(void* const* d_in, const int* in_sizes, int n_in,
                              void* d_out, int out_size, void* d_ws, size_t ws_size,
                              hipStream_t stream)
{
  const int*   edge_index = (const int*)d_in[0];
  const float* x      = (const float*)d_in[1];
  const int*   edge_id = (const int*)d_in[2];
  const float* W1     = (const float*)d_in[3];
  const float* a_src1 = (const float*)d_in[4];
  const float* a_dst1 = (const float*)d_in[5];
  const float* b1     = (const float*)d_in[6];
  const float* bn1_g  = (const float*)d_in[7];
  const float* bn1_b  = (const float*)d_in[8];
  const float* W2     = (const float*)d_in[9];
  const float* a_src2 = (const float*)d_in[10];
  const float* a_dst2 = (const float*)d_in[11];
  const float* b2     = (const float*)d_in[12];
  const float* bn2_g  = (const float*)d_in[13];
  const float* bn2_b  = (const float*)d_in[14];
  const float* lw1    = (const float*)d_in[15];
  const float* lb1    = (const float*)d_in[16];
  const float* bn3_g  = (const float*)d_in[17];
  const float* bn3_b  = (const float*)d_in[18];
  const float* lw2    = (const float*)d_in[19];
  const float* lb2    = (const float*)d_in[20];
  const float* bn4_g  = (const float*)d_in[21];
  const float* bn4_b  = (const float*)d_in[22];
  const float* fw     = (const float*)d_in[23];
  const float* fb     = (const float*)d_in[24];
  float* out = (float*)d_out;

  // ---- workspace arena (explicit aliasing) ----
  char* w = (char*)d_ws;
  ushort* xb     = (ushort*)(w + 0);
  ushort* hb     = (ushort*)(w + 57600000);
  float*  t_buf  = (float*)(w + 108800000);
  ushort* feat1b = (ushort*)(w + 160000000);
  ushort* feat2b = (ushort*)(w + 185600000);
  float*  z1     = (float*)(w + 0);               // aliases xb/hb/t (dead)
  ushort* z1b    = (ushort*)(w + 160000000);      // aliases feat1b (dead)
  float*  z2     = (float*)(w + 0);               // aliases z1 (dead)
  ushort* z2b    = (ushort*)(w + 227108864);
  int*    csr_src = (int*)(w + 294217728);
  int*    deg     = (int*)(w + 297700000);
  int*    rowptr  = (int*)(w + 297900000);
  int*    cursor  = (int*)(w + 298100008);
  float*  s_n     = (float*)(w + 298300008);
  float*  d_n     = (float*)(w + 298700008);
  double* stats   = (double*)(w + 299100008);     // 4 x 512 doubles
  ushort* W1T     = (ushort*)(w + 300000000);     // [512][576]
  ushort* W2T     = (ushort*)(w + 300600000);     // [512][256]
  ushort* LW1T    = (ushort*)(w + 300900000);     // [128][512]
  ushort* LW2T    = (ushort*)(w + 301040000);     // [128][128]
  ushort* FWT     = (ushort*)(w + 301080000);     // [128][128]

  double* st1 = stats,        *st2 = stats + 512;
  double* st3 = stats + 1024, *st4 = stats + 1536;

  dim3 b256(256);

  // ---- zero all stats once (each buffer written exactly once per call) ----
  hipMemsetAsync(stats, 0, 4 * 512 * sizeof(double), stream);

  // ---- weight prep + input convert ----
  prep_weights<<<2048, b256, 0, stream>>>(W1, W1T, W2, W2T, lw1, LW1T,
                                          lw2, LW2T, fw, FWT);
  conv_x<<<(NN * 144 + 255) / 256, b256, 0, stream>>>(x, xb);

  // ---- CSR build ----
  hipMemsetAsync(deg, 0, NN * sizeof(int), stream);
  deg_count<<<(ET + 255) / 256, b256, 0, stream>>>(edge_index, deg);
  scan_deg<<<1, 1024, 0, stream>>>(deg, rowptr, cursor);
  scatter_edges<<<(ET + 255) / 256, b256, 0, stream>>>(edge_index, cursor, csr_src);

  // ---- GAT layers ----
  gat_layer(xb, 576, W1T, a_src1, a_dst1, b1, bn1_g, bn1_b, rowptr, csr_src,
            hb, t_buf, feat1b, s_n, d_n, st1, stream);
  gat_layer(feat1b, 256, W2T, a_src2, a_dst2, b2, bn2_g, bn2_b, rowptr, csr_src,
            hb, t_buf, feat2b, s_n, d_n, st2, stream);

  // ---- pair MLP ----
  mfma_gemm<true, false, true><<<dim3(1, 2048), b256, 0, stream>>>(
      feat2b, LW1T, z1, NP, 128, 512, 128, lb1, edge_id, edge_id + NP, st3);
  bn_apply_relu_b4<<<(NP * 32 + 255) / 256, b256, 0, stream>>>(
      z1, z1b, st3, bn3_g, bn3_b, NP * 32, 128, 1.0f / NP);
  mfma_gemm<false, false, true><<<dim3(1, 2048), b256, 0, stream>>>(
      z1b, LW2T, z2, NP, 128, 128, 128, lb2, nullptr, nullptr, st4);
  bn_apply_relu_b4<<<(NP * 32 + 255) / 256, b256, 0, stream>>>(
      z2, z2b, st4, bn4_g, bn4_b, NP * 32, 128, 1.0f / NP);
  mfma_gemm<false, false, false><<<dim3(1, 2048), b256, 0, stream>>>(
      z2b, FWT, out, NP, 65, 128, 65, fb, nullptr, nullptr, nullptr);
}

// Round 17
// 1338.235 us; speedup vs baseline: 1.0488x; 1.0488x over previous
//
#include <hip/hip_runtime.h>

// ---------------------------------------------------------------------------
// Problem constants
// ---------------------------------------------------------------------------
constexpr int NN = 50000;            // nodes
constexpr int NE = 800000;           // edges (before self loops)
constexpr int NP = 262144;           // pairs
constexpr int ET = NE + NN;          // edges incl self loops

using short8 = __attribute__((ext_vector_type(8))) short;
using f32x4  = __attribute__((ext_vector_type(4))) float;

__device__ __forceinline__ ushort f2b(float f) {   // fp32 -> bf16 RNE
  unsigned u = __float_as_uint(f);
  return (ushort)((u + 0x7FFFu + ((u >> 16) & 1u)) >> 16);
}
__device__ __forceinline__ float b2f(ushort b) {
  return __uint_as_float(((unsigned)b) << 16);
}

// global -> LDS direct copy, 16B per lane (wave-linear LDS destination)
#define GLOAD_LDS16(gp, lp)                                                    \
  __builtin_amdgcn_global_load_lds(                                            \
      (const __attribute__((address_space(1))) void*)(gp),                     \
      (__attribute__((address_space(3))) void*)(lp), 16, 0, 0)

// ---------------------------------------------------------------------------
// bf16 MFMA GEMM: C[M,N] = A[M,Kpad] @ BT[Npad,Kpad]^T  (+bias)
// 128x128 block tile, BK=64, 4 waves of 64x64 — EXACT R12 geometry (measured
// best: total 1301us). Swizzle v1: source chunk c8s = c8 ^ (m&7), fragment
// slot = ja ^ (row&7) (same involution both sides, rule #21).
//
// R14 analysis: fp32 C-writes (z1/z2/out) use NONTEMPORAL stores.
// R14 PMC: pair-GEMM1 FETCH=117MB despite feat2b being only 25.6MB — the
// 134MB z1 write stream evicts feat2b from L3 between cross-block gather
// reuses, so gathers hit HBM at random-64B grain (~1.8TB/s => 146us). nt
// writes bypass L2/L3 -> feat2b stays resident -> gathers become L3 hits.
// bf16 outputs (hb) stay NORMAL: hb is re-read heavily and must cache.
// STATS: per-column sum/sumsq of output -> stats (N==128 only, M%128==0).
// ---------------------------------------------------------------------------
template<bool GATHER, bool OUT_BF16, bool STATS>
__global__ __launch_bounds__(256)
void mfma_gemm(const ushort* __restrict__ A, const ushort* __restrict__ BT,
               void* __restrict__ Cp, int M, int N, int Kpad, int Cld,
               const float* __restrict__ bias,
               const int* __restrict__ idx0, const int* __restrict__ idx1,
               double* __restrict__ stats)
{
  __shared__ __align__(16) ushort As[128 * 64];   // linear, BK=64
  __shared__ __align__(16) ushort Bs[128 * 64];
  __shared__ int idxs[256];
  const int tid = threadIdx.x;
  const int lane = tid & 63;
  const int wave = tid >> 6;
  const int row0 = blockIdx.y * 128, col0 = blockIdx.x * 128;
  const int wm = (wave >> 1) * 64, wn = (wave & 1) * 64;
  const int lrow = lane & 15, lk = (lane >> 4) * 8;

  if constexpr (GATHER) {
    if (tid < 128) {
      int r = row0 + tid;
      idxs[tid]       = (r < M) ? idx0[r] : 0;
      idxs[128 + tid] = (r < M) ? idx1[r] : 0;
    }
    __syncthreads();
  }

  f32x4 acc[4][4];
  #pragma unroll
  for (int i = 0; i < 4; ++i)
    #pragma unroll
    for (int j = 0; j < 4; ++j)
      acc[i][j] = (f32x4){0.f, 0.f, 0.f, 0.f};

  for (int kt = 0; kt < Kpad; kt += 64) {
    // ---- stage A: 1024 chunks of 16B, 4/thread; source chunk swizzled ----
    #pragma unroll
    for (int c = tid; c < 1024; c += 256) {
      int m = c >> 3, c8 = c & 7;             // LDS row, LDS chunk slot
      int c8s = c8 ^ (m & 7);                 // logical (global) chunk
      int r = row0 + m;
      if (r < M) {
        const ushort* sp;
        if (GATHER) {
          int kk = kt + c8s * 8;
          int node = (kk < 256) ? idxs[m] : idxs[128 + m];
          sp = A + (size_t)node * 256 + (kk & 255);
        } else {
          sp = A + (size_t)r * Kpad + kt + c8s * 8;
        }
        GLOAD_LDS16(sp, As + c * 8);
      }
    }
    // ---- stage B (in-bounds: BT padded to Npad x Kpad), same swizzle ----
    #pragma unroll
    for (int c = tid; c < 1024; c += 256) {
      int n = c >> 3, c8 = c & 7;
      int c8s = c8 ^ (n & 7);
      GLOAD_LDS16(BT + (size_t)(col0 + n) * Kpad + kt + c8s * 8, Bs + c * 8);
    }
    __syncthreads();

    #pragma unroll
    for (int kk2 = 0; kk2 < 64; kk2 += 32) {  // two K=32 sub-steps per tile
      const int ja = (kk2 + lk) >> 3;         // logical 16B chunk index
      short8 af[4], bfr[4];
      #pragma unroll
      for (int i = 0; i < 4; ++i) {
        int ra = wm + i * 16 + lrow;
        af[i] = *(const short8*)(As + ra * 64 + ((ja ^ (ra & 7)) << 3));
      }
      #pragma unroll
      for (int j = 0; j < 4; ++j) {
        int rb = wn + j * 16 + lrow;
        bfr[j] = *(const short8*)(Bs + rb * 64 + ((ja ^ (rb & 7)) << 3));
      }
      #pragma unroll
      for (int i = 0; i < 4; ++i)
        #pragma unroll
        for (int j = 0; j < 4; ++j)
          acc[i][j] = __builtin_amdgcn_mfma_f32_16x16x32_bf16(af[i], bfr[j],
                                                              acc[i][j], 0, 0, 0);
    }
    __syncthreads();
  }

  // epilogue: D mapping col=lane&15, row=(lane>>4)*4+reg
  float* sacc = (float*)As;                 // reuse LDS: [128]{sum,sumsq}
  if constexpr (STATS) {
    sacc[tid] = 0.f;
    __syncthreads();
  }
  float cs[4] = {0.f, 0.f, 0.f, 0.f}, cq[4] = {0.f, 0.f, 0.f, 0.f};
  #pragma unroll
  for (int i = 0; i < 4; ++i) {
    int r0 = row0 + wm + i * 16 + (lane >> 4) * 4;
    #pragma unroll
    for (int j = 0; j < 4; ++j) {
      int col = col0 + wn + j * 16 + lrow;
      if (col >= N) continue;
      float bv = bias ? bias[col] : 0.f;
      #pragma unroll
      for (int rg = 0; rg < 4; ++rg) {
        int row = r0 + rg;
        if (row >= M) continue;
        float val = acc[i][j][rg] + bv;
        if (OUT_BF16)
          ((ushort*)Cp)[(size_t)row * Cld + col] = f2b(val);
        else
          __builtin_nontemporal_store(val, &((float*)Cp)[(size_t)row * Cld + col]);
        if (STATS) { cs[j] += val; cq[j] += val * val; }
      }
    }
  }
  if constexpr (STATS) {
    #pragma unroll
    for (int j = 0; j < 4; ++j) {
      int cl = wn + j * 16 + lrow;          // local col (N==128, col0==0)
      atomicAdd(&sacc[2 * cl + 0], cs[j]);
      atomicAdd(&sacc[2 * cl + 1], cq[j]);
    }
    __syncthreads();
    if (tid < 128) {
      unsafeAtomicAdd(&stats[tid],       (double)sacc[2 * tid + 0]);
      unsafeAtomicAdd(&stats[128 + tid], (double)sacc[2 * tid + 1]);
    }
  }
}

// ---------------------------------------------------------------------------
// Weight prep: all 5 transposes in one kernel. W[K][N] -> BT[Npad][Kpad] bf16.
// ---------------------------------------------------------------------------
__global__ void prep_weights(const float* __restrict__ W1, ushort* __restrict__ W1T,
                             const float* __restrict__ W2, ushort* __restrict__ W2T,
                             const float* __restrict__ lw1, ushort* __restrict__ LW1T,
                             const float* __restrict__ lw2, ushort* __restrict__ LW2T,
                             const float* __restrict__ fw, ushort* __restrict__ FWT)
{
  int i = blockIdx.x * blockDim.x + threadIdx.x;
  const float* W; ushort* BT; int K, N, Kpad;
  if (i < 294912)      { W = W1;  BT = W1T;  K = 572; N = 512; Kpad = 576; }
  else if (i < 425984) { i -= 294912; W = W2;  BT = W2T;  K = 256; N = 512; Kpad = 256; }
  else if (i < 491520) { i -= 425984; W = lw1; BT = LW1T; K = 512; N = 128; Kpad = 512; }
  else if (i < 507904) { i -= 491520; W = lw2; BT = LW2T; K = 128; N = 128; Kpad = 128; }
  else                 { i -= 507904; W = fw;  BT = FWT;  K = 128; N = 65;  Kpad = 128; }
  int n = i / Kpad, k = i % Kpad;
  float v = (n < N && k < K) ? W[(size_t)k * N + n] : 0.f;
  BT[i] = f2b(v);
}

// x[NN][572] fp32 -> xb[NN][576] bf16 (zero padded), 4 cols/thread
__global__ void conv_x(const float* __restrict__ x, ushort* __restrict__ xb)
{
  int i = blockIdx.x * blockDim.x + threadIdx.x;
  if (i >= NN * 144) return;
  int r = i / 144, c4 = (i % 144) * 4;
  ushort4 o = {0, 0, 0, 0};
  if (c4 < 572) {           // c4 <= 568 -> full float4 in-bounds
    float4 v = *(const float4*)(x + (size_t)r * 572 + c4);
    o.x = f2b(v.x); o.y = f2b(v.y); o.z = f2b(v.z); o.w = f2b(v.w);
  }
  *(ushort4*)(xb + (size_t)r * 576 + c4) = o;
}

// ---------------------------------------------------------------------------
// CSR build (graph identical for both layers -> build once per call)
// ---------------------------------------------------------------------------
__global__ void deg_count(const int* __restrict__ ei, int* __restrict__ deg)
{
  int e = blockIdx.x * blockDim.x + threadIdx.x;
  if (e >= ET) return;
  int dst = (e < NE) ? ei[NE + e] : e - NE;
  atomicAdd(&deg[dst], 1);
}

__global__ __launch_bounds__(1024)
void scan_deg(const int* __restrict__ deg, int* __restrict__ rowptr,
              int* __restrict__ cursor)
{
  __shared__ int tot[1024];
  const int t = threadIdx.x;
  const int CH = (NN + 1023) / 1024;
  const int base = t * CH;
  int s = 0;
  for (int i = 0; i < CH; ++i) {
    int idx = base + i;
    if (idx < NN) s += deg[idx];
  }
  tot[t] = s;
  __syncthreads();
  for (int off = 1; off < 1024; off <<= 1) {
    int v = (t >= off) ? tot[t - off] : 0;
    __syncthreads();
    tot[t] += v;
    __syncthreads();
  }
  int run = (t == 0) ? 0 : tot[t - 1];
  for (int i = 0; i < CH; ++i) {
    int idx = base + i;
    if (idx <= NN) { rowptr[idx] = run; if (idx < NN) cursor[idx] = run; }
    if (idx < NN) run += deg[idx];
  }
}

__global__ void scatter_edges(const int* __restrict__ ei, int* __restrict__ cursor,
                              int* __restrict__ csr_src)
{
  int e = blockIdx.x * blockDim.x + threadIdx.x;
  if (e >= ET) return;
  int src, dst;
  if (e < NE) { src = ei[e]; dst = ei[NE + e]; }
  else        { src = dst = e - NE; }
  int pos = atomicAdd(&cursor[dst], 1);
  csr_src[pos] = src;
}

// ---------------------------------------------------------------------------
// GAT helpers (h in bf16)
// ---------------------------------------------------------------------------

// one wave per node, both heads: lane loads 8 contiguous bf16 (16 B)
__global__ void node_coeffs(const ushort* __restrict__ hb,
                            const float* __restrict__ a_src,
                            const float* __restrict__ a_dst,
                            float* __restrict__ s_n, float* __restrict__ d_n)
{
  int node = (blockIdx.x * blockDim.x + threadIdx.x) >> 6;
  int lane = threadIdx.x & 63;
  if (node >= NN) return;
  int head = lane >> 5;                 // lanes 0-31 head0, 32-63 head1
  int cidx = (lane * 8) & 255;          // col within head
  short8 hv = *(const short8*)(hb + (size_t)node * 512 + lane * 8);
  float4 a0 = *(const float4*)(a_src + head * 256 + cidx);
  float4 a1 = *(const float4*)(a_src + head * 256 + cidx + 4);
  float4 d0 = *(const float4*)(a_dst + head * 256 + cidx);
  float4 d1 = *(const float4*)(a_dst + head * 256 + cidx + 4);
  float h0 = b2f((ushort)hv[0]), h1 = b2f((ushort)hv[1]);
  float h2 = b2f((ushort)hv[2]), h3 = b2f((ushort)hv[3]);
  float h4 = b2f((ushort)hv[4]), h5 = b2f((ushort)hv[5]);
  float h6 = b2f((ushort)hv[6]), h7 = b2f((ushort)hv[7]);
  float ss = h0*a0.x + h1*a0.y + h2*a0.z + h3*a0.w
           + h4*a1.x + h5*a1.y + h6*a1.z + h7*a1.w;
  float dd = h0*d0.x + h1*d0.y + h2*d0.z + h3*d0.w
           + h4*d1.x + h5*d1.y + h6*d1.z + h7*d1.w;
  #pragma unroll
  for (int off = 16; off > 0; off >>= 1) {   // reduce within 32-lane half
    ss += __shfl_xor(ss, off);
    dd += __shfl_xor(dd, off);
  }
  if ((lane & 31) == 0) {
    s_n[node * 2 + head] = ss;
    d_n[node * 2 + head] = dd;
  }
}

// Measured-185us shape: one wave handles 4 dst nodes, 256-thread blocks,
// single full-range dispatch.
__global__ __launch_bounds__(256)
void gat_aggregate(const int* __restrict__ rowptr, const int* __restrict__ csr_src,
                   const ushort* __restrict__ hb,
                   const float* __restrict__ s_n, const float* __restrict__ d_n,
                   const float* __restrict__ bias, float* __restrict__ outp,
                   double* __restrict__ stats)
{
  __shared__ float sacc[512];               // [256] sum, [256] sumsq
  sacc[threadIdx.x] = 0.f;
  sacc[256 + threadIdx.x] = 0.f;
  __syncthreads();

  const int wave = threadIdx.x >> 6, lane = threadIdx.x & 63;
  const int base = blockIdx.x * 16 + wave * 4;
  const float4 bb = *(const float4*)(bias + lane * 4);
  const float2* sn2 = (const float2*)s_n;

  float ps[4] = {0.f, 0.f, 0.f, 0.f}, pq[4] = {0.f, 0.f, 0.f, 0.f};

  for (int n = 0; n < 4; ++n) {
    const int dst = base + n;
    if (dst >= NN) continue;                // wave-uniform
    const int beg = rowptr[dst], end = rowptr[dst + 1];
    const float d0 = d_n[dst * 2 + 0], d1 = d_n[dst * 2 + 1];

    // ---- scan 1: per-head max (strided across lanes) ----
    float m0 = -1e30f, m1 = -1e30f;
    for (int i = beg + lane; i < end; i += 64) {
      float2 sv = sn2[csr_src[i]];
      float a0 = sv.x + d0; a0 = a0 > 0.f ? a0 : 0.2f * a0;
      float a1 = sv.y + d1; a1 = a1 > 0.f ? a1 : 0.2f * a1;
      m0 = fmaxf(m0, a0); m1 = fmaxf(m1, a1);
    }
    #pragma unroll
    for (int off = 32; off > 0; off >>= 1) {
      m0 = fmaxf(m0, __shfl_xor(m0, off));
      m1 = fmaxf(m1, __shfl_xor(m1, off));
    }

    // ---- scan 2: unnormalized aggregation + partition sum, 4x unroll ----
    float z0 = 0.f, z1 = 0.f;
    float4 acc0 = {0.f, 0.f, 0.f, 0.f};
    float4 acc1 = {0.f, 0.f, 0.f, 0.f};
    int i = beg;
    for (; i + 4 <= end; i += 4) {          // 8 outstanding 8B gathers/lane
      int s[4];
      #pragma unroll
      for (int u = 0; u < 4; ++u) s[u] = csr_src[i + u];
      ushort4 h0[4], h1[4]; float2 sv[4];
      #pragma unroll
      for (int u = 0; u < 4; ++u) {
        h0[u] = *(const ushort4*)(hb + (size_t)s[u] * 512 + lane * 4);
        h1[u] = *(const ushort4*)(hb + (size_t)s[u] * 512 + 256 + lane * 4);
        sv[u] = sn2[s[u]];
      }
      #pragma unroll
      for (int u = 0; u < 4; ++u) {
        float a0 = sv[u].x + d0; a0 = a0 > 0.f ? a0 : 0.2f * a0;
        float a1 = sv[u].y + d1; a1 = a1 > 0.f ? a1 : 0.2f * a1;
        float e0 = __expf(a0 - m0), e1 = __expf(a1 - m1);
        z0 += e0; z1 += e1;
        acc0.x = fmaf(b2f(h0[u].x), e0, acc0.x);
        acc0.y = fmaf(b2f(h0[u].y), e0, acc0.y);
        acc0.z = fmaf(b2f(h0[u].z), e0, acc0.z);
        acc0.w = fmaf(b2f(h0[u].w), e0, acc0.w);
        acc1.x = fmaf(b2f(h1[u].x), e1, acc1.x);
        acc1.y = fmaf(b2f(h1[u].y), e1, acc1.y);
        acc1.z = fmaf(b2f(h1[u].z), e1, acc1.z);
        acc1.w = fmaf(b2f(h1[u].w), e1, acc1.w);
      }
    }
    for (; i < end; ++i) {
      int s = csr_src[i];
      float2 sv = sn2[s];
      ushort4 u0 = *(const ushort4*)(hb + (size_t)s * 512 + lane * 4);
      ushort4 u1 = *(const ushort4*)(hb + (size_t)s * 512 + 256 + lane * 4);
      float a0 = sv.x + d0; a0 = a0 > 0.f ? a0 : 0.2f * a0;
      float a1 = sv.y + d1; a1 = a1 > 0.f ? a1 : 0.2f * a1;
      float e0 = __expf(a0 - m0), e1 = __expf(a1 - m1);
      z0 += e0; z1 += e1;
      acc0.x = fmaf(b2f(u0.x), e0, acc0.x); acc0.y = fmaf(b2f(u0.y), e0, acc0.y);
      acc0.z = fmaf(b2f(u0.z), e0, acc0.z); acc0.w = fmaf(b2f(u0.w), e0, acc0.w);
      acc1.x = fmaf(b2f(u1.x), e1, acc1.x); acc1.y = fmaf(b2f(u1.y), e1, acc1.y);
      acc1.z = fmaf(b2f(u1.z), e1, acc1.z); acc1.w = fmaf(b2f(u1.w), e1, acc1.w);
    }

    const float rz0 = 1.f / (z0 + 1e-16f);
    const float rz1 = 1.f / (z1 + 1e-16f);
    float4 o;
    o.x = 0.5f * (acc0.x * rz0 + acc1.x * rz1) + bb.x;
    o.y = 0.5f * (acc0.y * rz0 + acc1.y * rz1) + bb.y;
    o.z = 0.5f * (acc0.z * rz0 + acc1.z * rz1) + bb.z;
    o.w = 0.5f * (acc0.w * rz0 + acc1.w * rz1) + bb.w;
    *(float4*)(outp + (size_t)dst * 256 + lane * 4) = o;

    ps[0] += o.x; ps[1] += o.y; ps[2] += o.z; ps[3] += o.w;
    pq[0] += o.x * o.x; pq[1] += o.y * o.y;
    pq[2] += o.z * o.z; pq[3] += o.w * o.w;
  }

  // one set of LDS atomics per wave
  const int c = lane * 4;
  atomicAdd(&sacc[c + 0], ps[0]); atomicAdd(&sacc[c + 1], ps[1]);
  atomicAdd(&sacc[c + 2], ps[2]); atomicAdd(&sacc[c + 3], ps[3]);
  atomicAdd(&sacc[256 + c + 0], pq[0]); atomicAdd(&sacc[256 + c + 1], pq[1]);
  atomicAdd(&sacc[256 + c + 2], pq[2]); atomicAdd(&sacc[256 + c + 3], pq[3]);
  __syncthreads();
  unsafeAtomicAdd(&stats[threadIdx.x],         (double)sacc[threadIdx.x]);
  unsafeAtomicAdd(&stats[256 + threadIdx.x],   (double)sacc[256 + threadIdx.x]);
}

// ---------------------------------------------------------------------------
// BatchNorm apply (+ReLU) -> bf16; scale/shift computed inline from stats
// ---------------------------------------------------------------------------
__global__ void bn_apply_relu_b4(const float* __restrict__ x, ushort* __restrict__ y,
                                 const double* __restrict__ stats,
                                 const float* __restrict__ g, const float* __restrict__ b,
                                 int total4, int cols, float inv_rows)
{
  int i = blockIdx.x * blockDim.x + threadIdx.x;
  if (i >= total4) return;
  int base = i * 4;
  int c = base % cols;                  // cols % 4 == 0 -> same row, 4 cols
  float4 xv = *(const float4*)(x + base);
  float4 gv = *(const float4*)(g + c);
  float4 bv = *(const float4*)(b + c);
  ushort4 o;
  #pragma unroll
  for (int k = 0; k < 4; ++k) {
    float mean = (float)(stats[c + k] * (double)inv_rows);
    float var = (float)(stats[cols + c + k] * (double)inv_rows) - mean * mean;
    float sc = ((const float*)&gv)[k] * rsqrtf(var + 1e-5f);
    float sh = ((const float*)&bv)[k] - mean * sc;
    float v = fmaxf(fmaf(((const float*)&xv)[k], sc, sh), 0.f);
    ((ushort*)&o)[k] = f2b(v);
  }
  *(ushort4*)(y + base) = o;
}

// ---------------------------------------------------------------------------
// Host-side GAT layer
// ---------------------------------------------------------------------------
static void gat_layer(const ushort* ain, int Kpad, const ushort* WT,
                      const float* asrc, const float* adst, const float* bias,
                      const float* bng, const float* bnb,
                      const int* rowptr, const int* csr_src,
                      ushort* hb, float* t, ushort* featb,
                      float* s_n, float* d_n, double* stats, hipStream_t st)
{
  dim3 b256(256);
  mfma_gemm<false, true, false><<<dim3(4, 391), b256, 0, st>>>(
      ain, WT, hb, NN, 512, Kpad, 512, nullptr, nullptr, nullptr, nullptr);
  node_coeffs<<<(NN + 3) / 4, b256, 0, st>>>(hb, asrc, adst, s_n, d_n);
  gat_aggregate<<<(NN + 15) / 16, b256, 0, st>>>(rowptr, csr_src, hb,
                                                 s_n, d_n, bias, t, stats);
  bn_apply_relu_b4<<<(NN * 64 + 255) / 256, b256, 0, st>>>(
      t, featb, stats, bng, bnb, NN * 64, 256, 1.0f / NN);
}

// ---------------------------------------------------------------------------
// kernel_launch
// ---------------------------------------------------------------------------
extern "C" void kernel_launch(void* const* d_in, const int* in_sizes, int n_in,
                              void* d_out, int out_size, void* d_ws, size_t ws_size,
                              hipStream_t stream)
{
  const int*   edge_index = (const int*)d_in[0];
  const float* x      = (const float*)d_in[1];
  const int*   edge_id = (const int*)d_in[2];
  const float* W1     = (const float*)d_in[3];
  const float* a_src1 = (const float*)d_in[4];
  const float* a_dst1 = (const float*)d_in[5];
  const float* b1     = (const float*)d_in[6];
  const float* bn1_g  = (const float*)d_in[7];
  const float* bn1_b  = (const float*)d_in[8];
  const float* W2     = (const float*)d_in[9];
  const float* a_src2 = (const float*)d_in[10];
  const float* a_dst2 = (const float*)d_in[11];
  const float* b2     = (const float*)d_in[12];
  const float* bn2_g  = (const float*)d_in[13];
  const float* bn2_b  = (const float*)d_in[14];
  const float* lw1    = (const float*)d_in[15];
  const float* lb1    = (const float*)d_in[16];
  const float* bn3_g  = (const float*)d_in[17];
  const float* bn3_b  = (const float*)d_in[18];
  const float* lw2    = (const float*)d_in[19];
  const float* lb2    = (const float*)d_in[20];
  const float* bn4_g  = (const float*)d_in[21];
  const float* bn4_b  = (const float*)d_in[22];
  const float* fw     = (const float*)d_in[23];
  const float* fb     = (const float*)d_in[24];
  float* out = (float*)d_out;

  // ---- workspace arena (explicit aliasing) ----
  char* w = (char*)d_ws;
  ushort* xb     = (ushort*)(w + 0);
  ushort* hb     = (ushort*)(w + 57600000);
  float*  t_buf  = (float*)(w + 108800000);
  ushort* feat1b = (ushort*)(w + 160000000);
  ushort* feat2b = (ushort*)(w + 185600000);
  float*  z1     = (float*)(w + 0);               // aliases xb/hb/t (dead)
  ushort* z1b    = (ushort*)(w + 160000000);      // aliases feat1b (dead)
  float*  z2     = (float*)(w + 0);               // aliases z1 (dead)
  ushort* z2b    = (ushort*)(w + 227108864);
  int*    csr_src = (int*)(w + 294217728);
  int*    deg     = (int*)(w + 297700000);
  int*    rowptr  = (int*)(w + 297900000);
  int*    cursor  = (int*)(w + 298100008);
  float*  s_n     = (float*)(w + 298300008);
  float*  d_n     = (float*)(w + 298700008);
  double* stats   = (double*)(w + 299100008);     // 4 x 512 doubles
  ushort* W1T     = (ushort*)(w + 300000000);     // [512][576]
  ushort* W2T     = (ushort*)(w + 300600000);     // [512][256]
  ushort* LW1T    = (ushort*)(w + 300900000);     // [128][512]
  ushort* LW2T    = (ushort*)(w + 301040000);     // [128][128]
  ushort* FWT     = (ushort*)(w + 301080000);     // [128][128]

  double* st1 = stats,        *st2 = stats + 512;
  double* st3 = stats + 1024, *st4 = stats + 1536;

  dim3 b256(256);

  // ---- zero all stats once (each buffer written exactly once per call) ----
  hipMemsetAsync(stats, 0, 4 * 512 * sizeof(double), stream);

  // ---- weight prep + input convert ----
  prep_weights<<<2048, b256, 0, stream>>>(W1, W1T, W2, W2T, lw1, LW1T,
                                          lw2, LW2T, fw, FWT);
  conv_x<<<(NN * 144 + 255) / 256, b256, 0, stream>>>(x, xb);

  // ---- CSR build ----
  hipMemsetAsync(deg, 0, NN * sizeof(int), stream);
  deg_count<<<(ET + 255) / 256, b256, 0, stream>>>(edge_index, deg);
  scan_deg<<<1, 1024, 0, stream>>>(deg, rowptr, cursor);
  scatter_edges<<<(ET + 255) / 256, b256, 0, stream>>>(edge_index, cursor, csr_src);

  // ---- GAT layers ----
  gat_layer(xb, 576, W1T, a_src1, a_dst1, b1, bn1_g, bn1_b, rowptr, csr_src,
            hb, t_buf, feat1b, s_n, d_n, st1, stream);
  gat_layer(feat1b, 256, W2T, a_src2, a_dst2, b2, bn2_g, bn2_b, rowptr, csr_src,
            hb, t_buf, feat2b, s_n, d_n, st2, stream);

  // ---- pair MLP ----
  mfma_gemm<true, false, true><<<dim3(1, 2048), b256, 0, stream>>>(
      feat2b, LW1T, z1, NP, 128, 512, 128, lb1, edge_id, edge_id + NP, st3);
  bn_apply_relu_b4<<<(NP * 32 + 255) / 256, b256, 0, stream>>>(
      z1, z1b, st3, bn3_g, bn3_b, NP * 32, 128, 1.0f / NP);
  mfma_gemm<false, false, true><<<dim3(1, 2048), b256, 0, stream>>>(
      z1b, LW2T, z2, NP, 128, 128, 128, lb2, nullptr, nullptr, st4);
  bn_apply_relu_b4<<<(NP * 32 + 255) / 256, b256, 0, stream>>>(
      z2, z2b, st4, bn4_g, bn4_b, NP * 32, 128, 1.0f / NP);
  mfma_gemm<false, false, false><<<dim3(1, 2048), b256, 0, stream>>>(
      z2b, FWT, out, NP, 65, 128, 65, fb, nullptr, nullptr, nullptr);
}

// Round 18
// 1297.448 us; speedup vs baseline: 1.0818x; 1.0314x over previous
//
#include <hip/hip_runtime.h>

// ---------------------------------------------------------------------------
// Problem constants
// ---------------------------------------------------------------------------
constexpr int NN = 50000;            // nodes
constexpr int NE = 800000;           // edges (before self loops)
constexpr int NP = 262144;           // pairs
constexpr int ET = NE + NN;          // edges incl self loops

using short8 = __attribute__((ext_vector_type(8))) short;
using f32x4  = __attribute__((ext_vector_type(4))) float;

__device__ __forceinline__ ushort f2b(float f) {   // fp32 -> bf16 RNE
  unsigned u = __float_as_uint(f);
  return (ushort)((u + 0x7FFFu + ((u >> 16) & 1u)) >> 16);
}
__device__ __forceinline__ float b2f(ushort b) {
  return __uint_as_float(((unsigned)b) << 16);
}

// global -> LDS direct copy, 16B per lane (wave-linear LDS destination)
#define GLOAD_LDS16(gp, lp)                                                    \
  __builtin_amdgcn_global_load_lds(                                            \
      (const __attribute__((address_space(1))) void*)(gp),                     \
      (__attribute__((address_space(3))) void*)(lp), 16, 0, 0)

// ---------------------------------------------------------------------------
// bf16 MFMA GEMM: C[M,N] = A[M,Kpad] @ BT[Npad,Kpad]^T  (+bias)
// 128x128 block tile, BK=64, 4 waves of 64x64 — EXACT R12 configuration
// (measured best: total 1301.1us). Swizzle v1: source chunk c8s = c8^(m&7),
// fragment slot = ja^(row&7) (same involution both sides, rule #21;
// R14 PMC verified SQ_LDS_BANK_CONFLICT == 0 with this scheme at BK=32;
// at BK=64 it measured -33.6us vs unswizzled).
// NOTE: plain fp32 C-stores. R17 measured nontemporal stores at +37us
// (L3 is memory-side on MI355X — nt can't protect gather reuse, and it
// forfeits bn_apply's L2/L3 hits on freshly written z1/z2). Reverted.
// STATS: per-column sum/sumsq of output -> stats (N==128 only, M%128==0).
// ---------------------------------------------------------------------------
template<bool GATHER, bool OUT_BF16, bool STATS>
__global__ __launch_bounds__(256)
void mfma_gemm(const ushort* __restrict__ A, const ushort* __restrict__ BT,
               void* __restrict__ Cp, int M, int N, int Kpad, int Cld,
               const float* __restrict__ bias,
               const int* __restrict__ idx0, const int* __restrict__ idx1,
               double* __restrict__ stats)
{
  __shared__ __align__(16) ushort As[128 * 64];   // linear, BK=64
  __shared__ __align__(16) ushort Bs[128 * 64];
  __shared__ int idxs[256];
  const int tid = threadIdx.x;
  const int lane = tid & 63;
  const int wave = tid >> 6;
  const int row0 = blockIdx.y * 128, col0 = blockIdx.x * 128;
  const int wm = (wave >> 1) * 64, wn = (wave & 1) * 64;
  const int lrow = lane & 15, lk = (lane >> 4) * 8;

  if constexpr (GATHER) {
    if (tid < 128) {
      int r = row0 + tid;
      idxs[tid]       = (r < M) ? idx0[r] : 0;
      idxs[128 + tid] = (r < M) ? idx1[r] : 0;
    }
    __syncthreads();
  }

  f32x4 acc[4][4];
  #pragma unroll
  for (int i = 0; i < 4; ++i)
    #pragma unroll
    for (int j = 0; j < 4; ++j)
      acc[i][j] = (f32x4){0.f, 0.f, 0.f, 0.f};

  for (int kt = 0; kt < Kpad; kt += 64) {
    // ---- stage A: 1024 chunks of 16B, 4/thread; source chunk swizzled ----
    #pragma unroll
    for (int c = tid; c < 1024; c += 256) {
      int m = c >> 3, c8 = c & 7;             // LDS row, LDS chunk slot
      int c8s = c8 ^ (m & 7);                 // logical (global) chunk
      int r = row0 + m;
      if (r < M) {
        const ushort* sp;
        if (GATHER) {
          int kk = kt + c8s * 8;
          int node = (kk < 256) ? idxs[m] : idxs[128 + m];
          sp = A + (size_t)node * 256 + (kk & 255);
        } else {
          sp = A + (size_t)r * Kpad + kt + c8s * 8;
        }
        GLOAD_LDS16(sp, As + c * 8);
      }
    }
    // ---- stage B (in-bounds: BT padded to Npad x Kpad), same swizzle ----
    #pragma unroll
    for (int c = tid; c < 1024; c += 256) {
      int n = c >> 3, c8 = c & 7;
      int c8s = c8 ^ (n & 7);
      GLOAD_LDS16(BT + (size_t)(col0 + n) * Kpad + kt + c8s * 8, Bs + c * 8);
    }
    __syncthreads();

    #pragma unroll
    for (int kk2 = 0; kk2 < 64; kk2 += 32) {  // two K=32 sub-steps per tile
      const int ja = (kk2 + lk) >> 3;         // logical 16B chunk index
      short8 af[4], bfr[4];
      #pragma unroll
      for (int i = 0; i < 4; ++i) {
        int ra = wm + i * 16 + lrow;
        af[i] = *(const short8*)(As + ra * 64 + ((ja ^ (ra & 7)) << 3));
      }
      #pragma unroll
      for (int j = 0; j < 4; ++j) {
        int rb = wn + j * 16 + lrow;
        bfr[j] = *(const short8*)(Bs + rb * 64 + ((ja ^ (rb & 7)) << 3));
      }
      #pragma unroll
      for (int i = 0; i < 4; ++i)
        #pragma unroll
        for (int j = 0; j < 4; ++j)
          acc[i][j] = __builtin_amdgcn_mfma_f32_16x16x32_bf16(af[i], bfr[j],
                                                              acc[i][j], 0, 0, 0);
    }
    __syncthreads();
  }

  // epilogue: D mapping col=lane&15, row=(lane>>4)*4+reg
  float* sacc = (float*)As;                 // reuse LDS: [128]{sum,sumsq}
  if constexpr (STATS) {
    sacc[tid] = 0.f;
    __syncthreads();
  }
  float cs[4] = {0.f, 0.f, 0.f, 0.f}, cq[4] = {0.f, 0.f, 0.f, 0.f};
  #pragma unroll
  for (int i = 0; i < 4; ++i) {
    int r0 = row0 + wm + i * 16 + (lane >> 4) * 4;
    #pragma unroll
    for (int j = 0; j < 4; ++j) {
      int col = col0 + wn + j * 16 + lrow;
      if (col >= N) continue;
      float bv = bias ? bias[col] : 0.f;
      #pragma unroll
      for (int rg = 0; rg < 4; ++rg) {
        int row = r0 + rg;
        if (row >= M) continue;
        float val = acc[i][j][rg] + bv;
        if (OUT_BF16)
          ((ushort*)Cp)[(size_t)row * Cld + col] = f2b(val);
        else
          ((float*)Cp)[(size_t)row * Cld + col] = val;
        if (STATS) { cs[j] += val; cq[j] += val * val; }
      }
    }
  }
  if constexpr (STATS) {
    #pragma unroll
    for (int j = 0; j < 4; ++j) {
      int cl = wn + j * 16 + lrow;          // local col (N==128, col0==0)
      atomicAdd(&sacc[2 * cl + 0], cs[j]);
      atomicAdd(&sacc[2 * cl + 1], cq[j]);
    }
    __syncthreads();
    if (tid < 128) {
      unsafeAtomicAdd(&stats[tid],       (double)sacc[2 * tid + 0]);
      unsafeAtomicAdd(&stats[128 + tid], (double)sacc[2 * tid + 1]);
    }
  }
}

// ---------------------------------------------------------------------------
// Weight prep: all 5 transposes in one kernel. W[K][N] -> BT[Npad][Kpad] bf16.
// ---------------------------------------------------------------------------
__global__ void prep_weights(const float* __restrict__ W1, ushort* __restrict__ W1T,
                             const float* __restrict__ W2, ushort* __restrict__ W2T,
                             const float* __restrict__ lw1, ushort* __restrict__ LW1T,
                             const float* __restrict__ lw2, ushort* __restrict__ LW2T,
                             const float* __restrict__ fw, ushort* __restrict__ FWT)
{
  int i = blockIdx.x * blockDim.x + threadIdx.x;
  const float* W; ushort* BT; int K, N, Kpad;
  if (i < 294912)      { W = W1;  BT = W1T;  K = 572; N = 512; Kpad = 576; }
  else if (i < 425984) { i -= 294912; W = W2;  BT = W2T;  K = 256; N = 512; Kpad = 256; }
  else if (i < 491520) { i -= 425984; W = lw1; BT = LW1T; K = 512; N = 128; Kpad = 512; }
  else if (i < 507904) { i -= 491520; W = lw2; BT = LW2T; K = 128; N = 128; Kpad = 128; }
  else                 { i -= 507904; W = fw;  BT = FWT;  K = 128; N = 65;  Kpad = 128; }
  int n = i / Kpad, k = i % Kpad;
  float v = (n < N && k < K) ? W[(size_t)k * N + n] : 0.f;
  BT[i] = f2b(v);
}

// x[NN][572] fp32 -> xb[NN][576] bf16 (zero padded), 4 cols/thread
__global__ void conv_x(const float* __restrict__ x, ushort* __restrict__ xb)
{
  int i = blockIdx.x * blockDim.x + threadIdx.x;
  if (i >= NN * 144) return;
  int r = i / 144, c4 = (i % 144) * 4;
  ushort4 o = {0, 0, 0, 0};
  if (c4 < 572) {           // c4 <= 568 -> full float4 in-bounds
    float4 v = *(const float4*)(x + (size_t)r * 572 + c4);
    o.x = f2b(v.x); o.y = f2b(v.y); o.z = f2b(v.z); o.w = f2b(v.w);
  }
  *(ushort4*)(xb + (size_t)r * 576 + c4) = o;
}

// ---------------------------------------------------------------------------
// CSR build (graph identical for both layers -> build once per call)
// ---------------------------------------------------------------------------
__global__ void deg_count(const int* __restrict__ ei, int* __restrict__ deg)
{
  int e = blockIdx.x * blockDim.x + threadIdx.x;
  if (e >= ET) return;
  int dst = (e < NE) ? ei[NE + e] : e - NE;
  atomicAdd(&deg[dst], 1);
}

__global__ __launch_bounds__(1024)
void scan_deg(const int* __restrict__ deg, int* __restrict__ rowptr,
              int* __restrict__ cursor)
{
  __shared__ int tot[1024];
  const int t = threadIdx.x;
  const int CH = (NN + 1023) / 1024;
  const int base = t * CH;
  int s = 0;
  for (int i = 0; i < CH; ++i) {
    int idx = base + i;
    if (idx < NN) s += deg[idx];
  }
  tot[t] = s;
  __syncthreads();
  for (int off = 1; off < 1024; off <<= 1) {
    int v = (t >= off) ? tot[t - off] : 0;
    __syncthreads();
    tot[t] += v;
    __syncthreads();
  }
  int run = (t == 0) ? 0 : tot[t - 1];
  for (int i = 0; i < CH; ++i) {
    int idx = base + i;
    if (idx <= NN) { rowptr[idx] = run; if (idx < NN) cursor[idx] = run; }
    if (idx < NN) run += deg[idx];
  }
}

__global__ void scatter_edges(const int* __restrict__ ei, int* __restrict__ cursor,
                              int* __restrict__ csr_src)
{
  int e = blockIdx.x * blockDim.x + threadIdx.x;
  if (e >= ET) return;
  int src, dst;
  if (e < NE) { src = ei[e]; dst = ei[NE + e]; }
  else        { src = dst = e - NE; }
  int pos = atomicAdd(&cursor[dst], 1);
  csr_src[pos] = src;
}

// ---------------------------------------------------------------------------
// GAT helpers (h in bf16)
// ---------------------------------------------------------------------------

// one wave per node, both heads: lane loads 8 contiguous bf16 (16 B)
__global__ void node_coeffs(const ushort* __restrict__ hb,
                            const float* __restrict__ a_src,
                            const float* __restrict__ a_dst,
                            float* __restrict__ s_n, float* __restrict__ d_n)
{
  int node = (blockIdx.x * blockDim.x + threadIdx.x) >> 6;
  int lane = threadIdx.x & 63;
  if (node >= NN) return;
  int head = lane >> 5;                 // lanes 0-31 head0, 32-63 head1
  int cidx = (lane * 8) & 255;          // col within head
  short8 hv = *(const short8*)(hb + (size_t)node * 512 + lane * 8);
  float4 a0 = *(const float4*)(a_src + head * 256 + cidx);
  float4 a1 = *(const float4*)(a_src + head * 256 + cidx + 4);
  float4 d0 = *(const float4*)(a_dst + head * 256 + cidx);
  float4 d1 = *(const float4*)(a_dst + head * 256 + cidx + 4);
  float h0 = b2f((ushort)hv[0]), h1 = b2f((ushort)hv[1]);
  float h2 = b2f((ushort)hv[2]), h3 = b2f((ushort)hv[3]);
  float h4 = b2f((ushort)hv[4]), h5 = b2f((ushort)hv[5]);
  float h6 = b2f((ushort)hv[6]), h7 = b2f((ushort)hv[7]);
  float ss = h0*a0.x + h1*a0.y + h2*a0.z + h3*a0.w
           + h4*a1.x + h5*a1.y + h6*a1.z + h7*a1.w;
  float dd = h0*d0.x + h1*d0.y + h2*d0.z + h3*d0.w
           + h4*d1.x + h5*d1.y + h6*d1.z + h7*d1.w;
  #pragma unroll
  for (int off = 16; off > 0; off >>= 1) {   // reduce within 32-lane half
    ss += __shfl_xor(ss, off);
    dd += __shfl_xor(dd, off);
  }
  if ((lane & 31) == 0) {
    s_n[node * 2 + head] = ss;
    d_n[node * 2 + head] = dd;
  }
}

// Measured-185us shape: one wave handles 4 dst nodes, 256-thread blocks,
// single full-range dispatch.
__global__ __launch_bounds__(256)
void gat_aggregate(const int* __restrict__ rowptr, const int* __restrict__ csr_src,
                   const ushort* __restrict__ hb,
                   const float* __restrict__ s_n, const float* __restrict__ d_n,
                   const float* __restrict__ bias, float* __restrict__ outp,
                   double* __restrict__ stats)
{
  __shared__ float sacc[512];               // [256] sum, [256] sumsq
  sacc[threadIdx.x] = 0.f;
  sacc[256 + threadIdx.x] = 0.f;
  __syncthreads();

  const int wave = threadIdx.x >> 6, lane = threadIdx.x & 63;
  const int base = blockIdx.x * 16 + wave * 4;
  const float4 bb = *(const float4*)(bias + lane * 4);
  const float2* sn2 = (const float2*)s_n;

  float ps[4] = {0.f, 0.f, 0.f, 0.f}, pq[4] = {0.f, 0.f, 0.f, 0.f};

  for (int n = 0; n < 4; ++n) {
    const int dst = base + n;
    if (dst >= NN) continue;                // wave-uniform
    const int beg = rowptr[dst], end = rowptr[dst + 1];
    const float d0 = d_n[dst * 2 + 0], d1 = d_n[dst * 2 + 1];

    // ---- scan 1: per-head max (strided across lanes) ----
    float m0 = -1e30f, m1 = -1e30f;
    for (int i = beg + lane; i < end; i += 64) {
      float2 sv = sn2[csr_src[i]];
      float a0 = sv.x + d0; a0 = a0 > 0.f ? a0 : 0.2f * a0;
      float a1 = sv.y + d1; a1 = a1 > 0.f ? a1 : 0.2f * a1;
      m0 = fmaxf(m0, a0); m1 = fmaxf(m1, a1);
    }
    #pragma unroll
    for (int off = 32; off > 0; off >>= 1) {
      m0 = fmaxf(m0, __shfl_xor(m0, off));
      m1 = fmaxf(m1, __shfl_xor(m1, off));
    }

    // ---- scan 2: unnormalized aggregation + partition sum, 4x unroll ----
    float z0 = 0.f, z1 = 0.f;
    float4 acc0 = {0.f, 0.f, 0.f, 0.f};
    float4 acc1 = {0.f, 0.f, 0.f, 0.f};
    int i = beg;
    for (; i + 4 <= end; i += 4) {          // 8 outstanding 8B gathers/lane
      int s[4];
      #pragma unroll
      for (int u = 0; u < 4; ++u) s[u] = csr_src[i + u];
      ushort4 h0[4], h1[4]; float2 sv[4];
      #pragma unroll
      for (int u = 0; u < 4; ++u) {
        h0[u] = *(const ushort4*)(hb + (size_t)s[u] * 512 + lane * 4);
        h1[u] = *(const ushort4*)(hb + (size_t)s[u] * 512 + 256 + lane * 4);
        sv[u] = sn2[s[u]];
      }
      #pragma unroll
      for (int u = 0; u < 4; ++u) {
        float a0 = sv[u].x + d0; a0 = a0 > 0.f ? a0 : 0.2f * a0;
        float a1 = sv[u].y + d1; a1 = a1 > 0.f ? a1 : 0.2f * a1;
        float e0 = __expf(a0 - m0), e1 = __expf(a1 - m1);
        z0 += e0; z1 += e1;
        acc0.x = fmaf(b2f(h0[u].x), e0, acc0.x);
        acc0.y = fmaf(b2f(h0[u].y), e0, acc0.y);
        acc0.z = fmaf(b2f(h0[u].z), e0, acc0.z);
        acc0.w = fmaf(b2f(h0[u].w), e0, acc0.w);
        acc1.x = fmaf(b2f(h1[u].x), e1, acc1.x);
        acc1.y = fmaf(b2f(h1[u].y), e1, acc1.y);
        acc1.z = fmaf(b2f(h1[u].z), e1, acc1.z);
        acc1.w = fmaf(b2f(h1[u].w), e1, acc1.w);
      }
    }
    for (; i < end; ++i) {
      int s = csr_src[i];
      float2 sv = sn2[s];
      ushort4 u0 = *(const ushort4*)(hb + (size_t)s * 512 + lane * 4);
      ushort4 u1 = *(const ushort4*)(hb + (size_t)s * 512 + 256 + lane * 4);
      float a0 = sv.x + d0; a0 = a0 > 0.f ? a0 : 0.2f * a0;
      float a1 = sv.y + d1; a1 = a1 > 0.f ? a1 : 0.2f * a1;
      float e0 = __expf(a0 - m0), e1 = __expf(a1 - m1);
      z0 += e0; z1 += e1;
      acc0.x = fmaf(b2f(u0.x), e0, acc0.x); acc0.y = fmaf(b2f(u0.y), e0, acc0.y);
      acc0.z = fmaf(b2f(u0.z), e0, acc0.z); acc0.w = fmaf(b2f(u0.w), e0, acc0.w);
      acc1.x = fmaf(b2f(u1.x), e1, acc1.x); acc1.y = fmaf(b2f(u1.y), e1, acc1.y);
      acc1.z = fmaf(b2f(u1.z), e1, acc1.z); acc1.w = fmaf(b2f(u1.w), e1, acc1.w);
    }

    const float rz0 = 1.f / (z0 + 1e-16f);
    const float rz1 = 1.f / (z1 + 1e-16f);
    float4 o;
    o.x = 0.5f * (acc0.x * rz0 + acc1.x * rz1) + bb.x;
    o.y = 0.5f * (acc0.y * rz0 + acc1.y * rz1) + bb.y;
    o.z = 0.5f * (acc0.z * rz0 + acc1.z * rz1) + bb.z;
    o.w = 0.5f * (acc0.w * rz0 + acc1.w * rz1) + bb.w;
    *(float4*)(outp + (size_t)dst * 256 + lane * 4) = o;

    ps[0] += o.x; ps[1] += o.y; ps[2] += o.z; ps[3] += o.w;
    pq[0] += o.x * o.x; pq[1] += o.y * o.y;
    pq[2] += o.z * o.z; pq[3] += o.w * o.w;
  }

  // one set of LDS atomics per wave
  const int c = lane * 4;
  atomicAdd(&sacc[c + 0], ps[0]); atomicAdd(&sacc[c + 1], ps[1]);
  atomicAdd(&sacc[c + 2], ps[2]); atomicAdd(&sacc[c + 3], ps[3]);
  atomicAdd(&sacc[256 + c + 0], pq[0]); atomicAdd(&sacc[256 + c + 1], pq[1]);
  atomicAdd(&sacc[256 + c + 2], pq[2]); atomicAdd(&sacc[256 + c + 3], pq[3]);
  __syncthreads();
  unsafeAtomicAdd(&stats[threadIdx.x],         (double)sacc[threadIdx.x]);
  unsafeAtomicAdd(&stats[256 + threadIdx.x],   (double)sacc[256 + threadIdx.x]);
}

// ---------------------------------------------------------------------------
// BatchNorm apply (+ReLU) -> bf16; scale/shift computed inline from stats
// ---------------------------------------------------------------------------
__global__ void bn_apply_relu_b4(const float* __restrict__ x, ushort* __restrict__ y,
                                 const double* __restrict__ stats,
                                 const float* __restrict__ g, const float* __restrict__ b,
                                 int total4, int cols, float inv_rows)
{
  int i = blockIdx.x * blockDim.x + threadIdx.x;
  if (i >= total4) return;
  int base = i * 4;
  int c = base % cols;                  // cols % 4 == 0 -> same row, 4 cols
  float4 xv = *(const float4*)(x + base);
  float4 gv = *(const float4*)(g + c);
  float4 bv = *(const float4*)(b + c);
  ushort4 o;
  #pragma unroll
  for (int k = 0; k < 4; ++k) {
    float mean = (float)(stats[c + k] * (double)inv_rows);
    float var = (float)(stats[cols + c + k] * (double)inv_rows) - mean * mean;
    float sc = ((const float*)&gv)[k] * rsqrtf(var + 1e-5f);
    float sh = ((const float*)&bv)[k] - mean * sc;
    float v = fmaxf(fmaf(((const float*)&xv)[k], sc, sh), 0.f);
    ((ushort*)&o)[k] = f2b(v);
  }
  *(ushort4*)(y + base) = o;
}

// ---------------------------------------------------------------------------
// Host-side GAT layer
// ---------------------------------------------------------------------------
static void gat_layer(const ushort* ain, int Kpad, const ushort* WT,
                      const float* asrc, const float* adst, const float* bias,
                      const float* bng, const float* bnb,
                      const int* rowptr, const int* csr_src,
                      ushort* hb, float* t, ushort* featb,
                      float* s_n, float* d_n, double* stats, hipStream_t st)
{
  dim3 b256(256);
  mfma_gemm<false, true, false><<<dim3(4, 391), b256, 0, st>>>(
      ain, WT, hb, NN, 512, Kpad, 512, nullptr, nullptr, nullptr, nullptr);
  node_coeffs<<<(NN + 3) / 4, b256, 0, st>>>(hb, asrc, adst, s_n, d_n);
  gat_aggregate<<<(NN + 15) / 16, b256, 0, st>>>(rowptr, csr_src, hb,
                                                 s_n, d_n, bias, t, stats);
  bn_apply_relu_b4<<<(NN * 64 + 255) / 256, b256, 0, st>>>(
      t, featb, stats, bng, bnb, NN * 64, 256, 1.0f / NN);
}

// ---------------------------------------------------------------------------
// kernel_launch
// ---------------------------------------------------------------------------
extern "C" void kernel_launch(void* const* d_in, const int* in_sizes, int n_in,
                              void* d_out, int out_size, void* d_ws, size_t ws_size,
                              hipStream_t stream)
{
  const int*   edge_index = (const int*)d_in[0];
  const float* x      = (const float*)d_in[1];
  const int*   edge_id = (const int*)d_in[2];
  const float* W1     = (const float*)d_in[3];
  const float* a_src1 = (const float*)d_in[4];
  const float* a_dst1 = (const float*)d_in[5];
  const float* b1     = (const float*)d_in[6];
  const float* bn1_g  = (const float*)d_in[7];
  const float* bn1_b  = (const float*)d_in[8];
  const float* W2     = (const float*)d_in[9];
  const float* a_src2 = (const float*)d_in[10];
  const float* a_dst2 = (const float*)d_in[11];
  const float* b2     = (const float*)d_in[12];
  const float* bn2_g  = (const float*)d_in[13];
  const float* bn2_b  = (const float*)d_in[14];
  const float* lw1    = (const float*)d_in[15];
  const float* lb1    = (const float*)d_in[16];
  const float* bn3_g  = (const float*)d_in[17];
  const float* bn3_b  = (const float*)d_in[18];
  const float* lw2    = (const float*)d_in[19];
  const float* lb2    = (const float*)d_in[20];
  const float* bn4_g  = (const float*)d_in[21];
  const float* bn4_b  = (const float*)d_in[22];
  const float* fw     = (const float*)d_in[23];
  const float* fb     = (const float*)d_in[24];
  float* out = (float*)d_out;

  // ---- workspace arena (explicit aliasing) ----
  char* w = (char*)d_ws;
  ushort* xb     = (ushort*)(w + 0);
  ushort* hb     = (ushort*)(w + 57600000);
  float*  t_buf  = (float*)(w + 108800000);
  ushort* feat1b = (ushort*)(w + 160000000);
  ushort* feat2b = (ushort*)(w + 185600000);
  float*  z1     = (float*)(w + 0);               // aliases xb/hb/t (dead)
  ushort* z1b    = (ushort*)(w + 160000000);      // aliases feat1b (dead)
  float*  z2     = (float*)(w + 0);               // aliases z1 (dead)
  ushort* z2b    = (ushort*)(w + 227108864);
  int*    csr_src = (int*)(w + 294217728);
  int*    deg     = (int*)(w + 297700000);
  int*    rowptr  = (int*)(w + 297900000);
  int*    cursor  = (int*)(w + 298100008);
  float*  s_n     = (float*)(w + 298300008);
  float*  d_n     = (float*)(w + 298700008);
  double* stats   = (double*)(w + 299100008);     // 4 x 512 doubles
  ushort* W1T     = (ushort*)(w + 300000000);     // [512][576]
  ushort* W2T     = (ushort*)(w + 300600000);     // [512][256]
  ushort* LW1T    = (ushort*)(w + 300900000);     // [128][512]
  ushort* LW2T    = (ushort*)(w + 301040000);     // [128][128]
  ushort* FWT     = (ushort*)(w + 301080000);     // [128][128]

  double* st1 = stats,        *st2 = stats + 512;
  double* st3 = stats + 1024, *st4 = stats + 1536;

  dim3 b256(256);

  // ---- zero all stats once (each buffer written exactly once per call) ----
  hipMemsetAsync(stats, 0, 4 * 512 * sizeof(double), stream);

  // ---- weight prep + input convert ----
  prep_weights<<<2048, b256, 0, stream>>>(W1, W1T, W2, W2T, lw1, LW1T,
                                          lw2, LW2T, fw, FWT);
  conv_x<<<(NN * 144 + 255) / 256, b256, 0, stream>>>(x, xb);

  // ---- CSR build ----
  hipMemsetAsync(deg, 0, NN * sizeof(int), stream);
  deg_count<<<(ET + 255) / 256, b256, 0, stream>>>(edge_index, deg);
  scan_deg<<<1, 1024, 0, stream>>>(deg, rowptr, cursor);
  scatter_edges<<<(ET + 255) / 256, b256, 0, stream>>>(edge_index, cursor, csr_src);

  // ---- GAT layers ----
  gat_layer(xb, 576, W1T, a_src1, a_dst1, b1, bn1_g, bn1_b, rowptr, csr_src,
            hb, t_buf, feat1b, s_n, d_n, st1, stream);
  gat_layer(feat1b, 256, W2T, a_src2, a_dst2, b2, bn2_g, bn2_b, rowptr, csr_src,
            hb, t_buf, feat2b, s_n, d_n, st2, stream);

  // ---- pair MLP ----
  mfma_gemm<true, false, true><<<dim3(1, 2048), b256, 0, stream>>>(
      feat2b, LW1T, z1, NP, 128, 512, 128, lb1, edge_id, edge_id + NP, st3);
  bn_apply_relu_b4<<<(NP * 32 + 255) / 256, b256, 0, stream>>>(
      z1, z1b, st3, bn3_g, bn3_b, NP * 32, 128, 1.0f / NP);
  mfma_gemm<false, false, true><<<dim3(1, 2048), b256, 0, stream>>>(
      z1b, LW2T, z2, NP, 128, 128, 128, lb2, nullptr, nullptr, st4);
  bn_apply_relu_b4<<<(NP * 32 + 255) / 256, b256, 0, stream>>>(
      z2, z2b, st4, bn4_g, bn4_b, NP * 32, 128, 1.0f / NP);
  mfma_gemm<false, false, false><<<dim3(1, 2048), b256, 0, stream>>>(
      z2b, FWT, out, NP, 65, 128, 65, fb, nullptr, nullptr, nullptr);
}